// Round 2
// baseline (87.280 us; speedup 1.0000x reference)
//
#include <hip/hip_runtime.h>
#include <stdint.h>
#include <stddef.h>

// ---- problem constants ----
#define NBATCH 2
#define NPTS   120000
#define T_SLOTS 100
#define PMAX   12000
#define NXG    500
#define NYG    500
#define NBINS  (NXG*NYG)     // 250000
#define SCAN_B 512
#define NBLK   ((NBINS + SCAN_B - 1)/SCAN_B)   // 489

// ---- workspace layout (bytes) ----
#define WS_CNT     ((size_t)0)                                   // 2*NBINS*4     = 2,000,000
#define WS_SLOT    (WS_CNT   + (size_t)NBATCH*NBINS*4)           // 2*PMAX*4      =    96,000
#define WS_ZEROEND (WS_SLOT  + (size_t)NBATCH*PMAX*4)            // zero region: [0, WS_ZEROEND)
#define WS_RANK    (WS_ZEROEND)                                   // 2*NBINS*4
#define WS_KEYPT   (WS_RANK  + (size_t)NBATCH*NBINS*4)           // 2*NPTS*4
#define WS_PILKEY  (WS_KEYPT + (size_t)NBATCH*NPTS*4)            // 2*PMAX*4
#define WS_PIDX    (WS_PILKEY+ (size_t)NBATCH*PMAX*4)            // 2*PMAX*T*4 = 9,600,000
#define WS_BSUM    (WS_PIDX  + (size_t)NBATCH*PMAX*T_SLOTS*4)    // 2*512*4
#define WS_BOFF    (WS_BSUM  + (size_t)NBATCH*SCAN_B*4)          // 2*512*4
#define WS_PTOT    (WS_BOFF  + (size_t)NBATCH*SCAN_B*4)          // 2*4
#define WS_NEEDED  (WS_PTOT  + (size_t)NBATCH*4)

// ---------------- kernels ----------------

__global__ void k_key(const float* __restrict__ pts, int* __restrict__ keypt,
                      int* __restrict__ cnt) {
    int i = blockIdx.x * blockDim.x + threadIdx.x;
    if (i >= NBATCH * NPTS) return;
    int b = i / NPTS;
    const float* p = pts + (size_t)i * 4;
    float x = p[0], y = p[1], z = p[2];
    bool valid = (x >= -40.0f) && (x < 40.0f) &&
                 (y >= -40.0f) && (y < 40.0f) &&
                 (z >= -3.0f)  && (z < 1.0f);
    int key = -1;
    if (valid) {
        float fx = floorf((x - (-40.0f)) / 0.16f);
        float fy = floorf((y - (-40.0f)) / 0.16f);
        fx = fminf(fmaxf(fx, 0.0f), (float)(NXG - 1));
        fy = fminf(fmaxf(fy, 0.0f), (float)(NYG - 1));
        key = (int)fx * NYG + (int)fy;
        atomicAdd(&cnt[b * NBINS + key], 1);
    }
    keypt[i] = key;
}

__global__ void k_scan1(const int* __restrict__ cnt, int* __restrict__ bsum) {
    __shared__ int sh[SCAN_B];
    int b = blockIdx.y;
    int bin = blockIdx.x * SCAN_B + threadIdx.x;
    int pres = (bin < NBINS && cnt[b * NBINS + bin] > 0) ? 1 : 0;
    sh[threadIdx.x] = pres;
    __syncthreads();
    for (int s = SCAN_B / 2; s > 0; s >>= 1) {
        if (threadIdx.x < s) sh[threadIdx.x] += sh[threadIdx.x + s];
        __syncthreads();
    }
    if (threadIdx.x == 0) bsum[b * SCAN_B + blockIdx.x] = sh[0];
}

__global__ void k_scan2(const int* __restrict__ bsum, int* __restrict__ boff,
                        int* __restrict__ ptot) {
    __shared__ int sh[SCAN_B];
    int b = blockIdx.x;
    int v = (threadIdx.x < NBLK) ? bsum[b * SCAN_B + threadIdx.x] : 0;
    sh[threadIdx.x] = v;
    __syncthreads();
    for (int s = 1; s < SCAN_B; s <<= 1) {
        int t = (threadIdx.x >= s) ? sh[threadIdx.x - s] : 0;
        __syncthreads();
        sh[threadIdx.x] += t;
        __syncthreads();
    }
    if (threadIdx.x < NBLK) boff[b * SCAN_B + threadIdx.x] = sh[threadIdx.x] - v;
    if (threadIdx.x == NBLK - 1) ptot[b] = sh[threadIdx.x];
}

__global__ void k_scan3(const int* __restrict__ cnt, const int* __restrict__ boff,
                        int* __restrict__ rank) {
    __shared__ int sh[SCAN_B];
    int b = blockIdx.y;
    int bin = blockIdx.x * SCAN_B + threadIdx.x;
    int pres = (bin < NBINS && cnt[b * NBINS + bin] > 0) ? 1 : 0;
    sh[threadIdx.x] = pres;
    __syncthreads();
    for (int s = 1; s < SCAN_B; s <<= 1) {
        int t = (threadIdx.x >= s) ? sh[threadIdx.x - s] : 0;
        __syncthreads();
        sh[threadIdx.x] += t;
        __syncthreads();
    }
    if (bin < NBINS)
        rank[b * NBINS + bin] = boff[b * SCAN_B + blockIdx.x] + sh[threadIdx.x] - pres;
}

__global__ void k_fill(const int* __restrict__ keypt, const int* __restrict__ cnt,
                       const int* __restrict__ rank, int* __restrict__ slotctr,
                       int* __restrict__ pilkey, int* __restrict__ pidx) {
    int i = blockIdx.x * blockDim.x + threadIdx.x;
    if (i >= NBATCH * NPTS) return;
    int key = keypt[i];
    if (key < 0) return;
    int b = i / NPTS;
    int j = i - b * NPTS;
    int c = cnt[b * NBINS + key];
    int r = rank[b * NBINS + key];
    if (r >= PMAX) return;
    pilkey[b * PMAX + r] = key;   // all writers store the same value
    if (c <= T_SLOTS) {
        int t = atomicAdd(&slotctr[b * PMAX + r], 1);
        pidx[((size_t)(b * PMAX + r)) * T_SLOTS + t] = j;
    } else {
        // rare overflow pillar: exact first-T-by-original-index selection
        const int* kp = keypt + (size_t)b * NPTS;
        int intra = 0;
        for (int q = 0; q < j; ++q) intra += (kp[q] == key);
        if (intra < T_SLOTS)
            pidx[((size_t)(b * PMAX + r)) * T_SLOTS + intra] = j;
    }
}

__global__ __launch_bounds__(64)
void k_feats(const float* __restrict__ pts,
             const float* __restrict__ w1, const float* __restrict__ g1,
             const float* __restrict__ b1, const float* __restrict__ m1,
             const float* __restrict__ v1,
             const float* __restrict__ w2, const float* __restrict__ g2,
             const float* __restrict__ b2, const float* __restrict__ m2,
             const float* __restrict__ v2,
             const int* __restrict__ cnt, const int* __restrict__ pilkey,
             const int* __restrict__ pidx, const int* __restrict__ ptot,
             float* __restrict__ out) {
    int blk = blockIdx.x;
    int b = blk / PMAX;
    int r = blk - b * PMAX;
    int o = threadIdx.x;   // output channel 0..63

    float* feats  = out;                                   // [B][PMAX][64]
    float* coords = out + (size_t)NBATCH * PMAX * 64;      // [B][PMAX][3]

    int pt_eff = ptot[b];
    if (pt_eff > PMAX) pt_eff = PMAX;

    size_t frow = ((size_t)b * PMAX + r) * 64;
    size_t crow = ((size_t)b * PMAX + r) * 3;

    if (r >= pt_eff) {
        feats[frow + o] = 0.0f;
        if (o < 3) coords[crow + o] = (o == 0) ? (float)b : 0.0f;
        return;
    }

    int key = pilkey[b * PMAX + r];
    int xi = key / NYG;
    int yi = key - xi * NYG;
    float xc = (float)xi * 0.16f + (-40.0f) + 0.08f;
    float yc = (float)yi * 0.16f + (-40.0f) + 0.08f;

    int c = cnt[b * NBINS + key];
    int pc = (c < T_SLOTS) ? c : T_SLOTS;

    // fold BN into the linear layers
    float s1 = g1[o] / sqrtf(v1[o] + 1e-5f);
    float w1r[8];
    #pragma unroll
    for (int cc = 0; cc < 8; ++cc) w1r[cc] = w1[o * 8 + cc] * s1;
    float b1f = b1[o] - m1[o] * s1;

    float s2 = g2[o] / sqrtf(v2[o] + 1e-5f);
    float w2r[64];
    #pragma unroll
    for (int k = 0; k < 64; ++k) w2r[k] = w2[o * 64 + k] * s2;
    float b2f = b2[o] - m2[o] * s2;

    __shared__ float h1s[64];
    float acc = 0.0f;   // all slot outputs are post-ReLU (>=0)

    for (int s = 0; s <= pc; ++s) {
        if (s == pc && pc >= T_SLOTS) break;   // no empty-slot feature when full
        float pin0, pin1, pin2, pin3;
        if (s < pc) {
            int j = pidx[((size_t)(b * PMAX + r)) * T_SLOTS + s];
            const float* P = pts + ((size_t)b * NPTS + j) * 4;
            pin0 = P[0]; pin1 = P[1]; pin2 = P[2]; pin3 = P[3];
        } else {
            pin0 = 0.0f; pin1 = 0.0f; pin2 = 0.0f; pin3 = 0.0f;
        }
        float pin4 = xc, pin5 = yc, pin6 = pin0 - xc, pin7 = pin1 - yc;

        float h = b1f;
        h += w1r[0] * pin0; h += w1r[1] * pin1; h += w1r[2] * pin2; h += w1r[3] * pin3;
        h += w1r[4] * pin4; h += w1r[5] * pin5; h += w1r[6] * pin6; h += w1r[7] * pin7;
        h = fmaxf(h, 0.0f);

        __syncthreads();
        h1s[o] = h;
        __syncthreads();

        float h2 = b2f;
        #pragma unroll
        for (int k = 0; k < 64; ++k) h2 += w2r[k] * h1s[k];
        h2 = fmaxf(h2, 0.0f);
        acc = fmaxf(acc, h2);
    }

    feats[frow + o] = acc;
    if (o < 3)
        coords[crow + o] = (o == 0) ? (float)b : ((o == 1) ? (float)xi : (float)yi);
}

// ---------------- launcher ----------------

extern "C" void kernel_launch(void* const* d_in, const int* in_sizes, int n_in,
                              void* d_out, int out_size, void* d_ws, size_t ws_size,
                              hipStream_t stream) {
    if (ws_size < WS_NEEDED) return;   // safety: avoid scratch corruption

    const float* pts = (const float*)d_in[0];
    const float* w1  = (const float*)d_in[1];
    const float* g1  = (const float*)d_in[2];
    const float* b1  = (const float*)d_in[3];
    const float* m1  = (const float*)d_in[4];
    const float* v1  = (const float*)d_in[5];
    const float* w2  = (const float*)d_in[6];
    const float* g2  = (const float*)d_in[7];
    const float* b2  = (const float*)d_in[8];
    const float* m2  = (const float*)d_in[9];
    const float* v2  = (const float*)d_in[10];

    char* ws = (char*)d_ws;
    int* cnt     = (int*)(ws + WS_CNT);
    int* slotctr = (int*)(ws + WS_SLOT);
    int* rank    = (int*)(ws + WS_RANK);
    int* keypt   = (int*)(ws + WS_KEYPT);
    int* pilkey  = (int*)(ws + WS_PILKEY);
    int* pidx    = (int*)(ws + WS_PIDX);
    int* bsum    = (int*)(ws + WS_BSUM);
    int* boff    = (int*)(ws + WS_BOFF);
    int* ptot    = (int*)(ws + WS_PTOT);

    float* out = (float*)d_out;

    // zero cnt + slotctr each launch (deterministic)
    hipMemsetAsync(ws + WS_CNT, 0, WS_ZEROEND - WS_CNT, stream);

    int npt = NBATCH * NPTS;
    dim3 blk256(256);
    dim3 grdPts((npt + 255) / 256);
    hipLaunchKernelGGL(k_key, grdPts, blk256, 0, stream, pts, keypt, cnt);

    dim3 grdScan(NBLK, NBATCH);
    hipLaunchKernelGGL(k_scan1, grdScan, dim3(SCAN_B), 0, stream, cnt, bsum);
    hipLaunchKernelGGL(k_scan2, dim3(NBATCH), dim3(SCAN_B), 0, stream, bsum, boff, ptot);
    hipLaunchKernelGGL(k_scan3, grdScan, dim3(SCAN_B), 0, stream, cnt, boff, rank);

    hipLaunchKernelGGL(k_fill, grdPts, blk256, 0, stream,
                       keypt, cnt, rank, slotctr, pilkey, pidx);

    hipLaunchKernelGGL(k_feats, dim3(NBATCH * PMAX), dim3(64), 0, stream,
                       pts, w1, g1, b1, m1, v1, w2, g2, b2, m2, v2,
                       cnt, pilkey, pidx, ptot, out);
}